// Round 7
// baseline (634.814 us; speedup 1.0000x reference)
//
#include <hip/hip_runtime.h>
#include <hip/hip_bf16.h>
#include <stdint.h>

// MLA forward, bf16 MFMA pipeline.
// Shapes: B=1 S=2048 HID=2048 H=16 QLR=1536 KVLR=512 NOPE=128 ROPE=64 VD=128 QKD=192.
// Attention = materialized-S: causal QK GEMM -> row softmax -> K-clamped PV GEMM.

using bf16 = __hip_bfloat16;
typedef __bf16 bf16x8 __attribute__((ext_vector_type(8)));
typedef __bf16 bf16x4 __attribute__((ext_vector_type(4)));
typedef float f32x4 __attribute__((ext_vector_type(4)));

#define S_LEN 2048
#define NHEAD 16

static __device__ __forceinline__ void gload16(const void* g, void* l) {
  __builtin_amdgcn_global_load_lds(
      (const __attribute__((address_space(1))) unsigned int*)g,
      (__attribute__((address_space(3))) unsigned int*)l, 16, 0, 0);
}

// ---------------- fp32 -> bf16 convert, 4-wide, optional row padding --------
__global__ void cvt_pad4(const float* __restrict__ src, bf16* __restrict__ dst,
                         int rows, int cols, int rowspad) {
  size_t total = ((size_t)rowspad * cols) >> 2;
  for (size_t i = (size_t)blockIdx.x * blockDim.x + threadIdx.x; i < total;
       i += (size_t)gridDim.x * blockDim.x) {
    size_t e = i << 2;
    int r = (int)(e / cols);
    int c = (int)(e % cols);
    float4 v;
    if (r < rows) v = *(const float4*)(src + (size_t)r * cols + c);
    else          v = make_float4(0.f, 0.f, 0.f, 0.f);
    bf16x4 o;
    o[0] = (__bf16)__float2bfloat16(v.x);
    o[1] = (__bf16)__float2bfloat16(v.y);
    o[2] = (__bf16)__float2bfloat16(v.z);
    o[3] = (__bf16)__float2bfloat16(v.w);
    *(bf16x4*)(dst + e) = o;
  }
}

// ---------------- wkv_bT[h][c][d] = wkv_b[h*256+d][c], d<128 ----------------
__global__ void mk_wkvbT(const bf16* __restrict__ wkvb, bf16* __restrict__ wt) {
  size_t total = 16ull * 512 * 128;
  for (size_t i = (size_t)blockIdx.x * blockDim.x + threadIdx.x; i < total;
       i += (size_t)gridDim.x * blockDim.x) {
    int h = (int)(i >> 16);          // 512*128
    int c = (int)((i >> 7) & 511);
    int d = (int)(i & 127);
    wt[i] = wkvb[((size_t)(h * 256 + d)) * 512 + c];
  }
}

// ---------------- row RMSNorm (bf16 in -> bf16 out) -------------------------
__global__ void rmsnorm_bf16(const bf16* __restrict__ in, const float* __restrict__ w,
                             bf16* __restrict__ out, int cols) {
  const int r = blockIdx.x, tid = threadIdx.x;
  const bf16* row = in + (size_t)r * cols;
  float ss = 0.f;
  for (int c = tid; c < cols; c += 256) {
    float v = __bfloat162float(row[c]);
    ss += v * v;
  }
  for (int m = 32; m >= 1; m >>= 1) ss += __shfl_xor(ss, m, 64);
  __shared__ float red[4];
  if ((tid & 63) == 0) red[tid >> 6] = ss;
  __syncthreads();
  ss = red[0] + red[1] + red[2] + red[3];
  float inv = rsqrtf(ss / (float)cols + 1e-6f);
  for (int c = tid; c < cols; c += 256)
    out[(size_t)r * cols + c] = __float2bfloat16(__bfloat162float(row[c]) * inv * w[c]);
}

// ---------------- kv post: rmsnorm(kv) + rope(k_pe) -> keff [t][576] --------
__global__ void kv_post(const float* __restrict__ kvf, const float* __restrict__ kvw,
                        bf16* __restrict__ keff) {
  const int t = blockIdx.x, tid = threadIdx.x;
  const float* row = kvf + (size_t)t * 640;
  float ss = 0.f;
  for (int c = tid; c < 512; c += 256) { float v = row[c]; ss += v * v; }
  for (int m = 32; m >= 1; m >>= 1) ss += __shfl_xor(ss, m, 64);
  __shared__ float red[4];
  if ((tid & 63) == 0) red[tid >> 6] = ss;
  __syncthreads();
  ss = red[0] + red[1] + red[2] + red[3];
  float inv = rsqrtf(ss * (1.0f / 512.0f) + 1e-6f);
  for (int c = tid; c < 512; c += 256)
    keff[(size_t)t * 576 + c] = __float2bfloat16(row[c] * inv * kvw[c]);
  if (tid < 64) {
    int j = tid, fr = j & 31;
    float freq = expf(-(float)fr * (1.0f / 32.0f) * 9.210340371976184f); // ln(10000)
    float ang = (float)t * freq;
    float cs = cosf(ang), sn = sinf(ang);
    float x1 = row[512 + j];
    float x2 = row[512 + (j < 32 ? j + 32 : j - 32)];
    float v = x1 * cs + (j < 32 ? -x2 : x2) * sn;
    keff[(size_t)t * 576 + 512 + j] = __float2bfloat16(v);
  }
}

// ---------------- q post: rope(q_pe) -> Qeff[h][s][512..576] ----------------
__global__ void q_post(const bf16* __restrict__ q, bf16* __restrict__ Qeff) {
  const int s = blockIdx.x, tid = threadIdx.x;
  for (int idx = tid; idx < 1024; idx += 256) {
    int h = idx >> 6, j = idx & 63, fr = j & 31;
    float freq = expf(-(float)fr * (1.0f / 32.0f) * 9.210340371976184f);
    float ang = (float)s * freq;
    float cs = cosf(ang), sn = sinf(ang);
    float x1 = __bfloat162float(q[(size_t)s * 3072 + h * 192 + 128 + j]);
    float x2 = __bfloat162float(q[(size_t)s * 3072 + h * 192 + 128 + (j < 32 ? j + 32 : j - 32)]);
    float v = x1 * cs + (j < 32 ? -x2 : x2) * sn;
    Qeff[((size_t)h * S_LEN + s) * 576 + 512 + j] = __float2bfloat16(v);
  }
}

// ---------------- kvT[c][t] = keff[t][c], c<512 (32x32 LDS transpose) -------
__global__ void transpose_k(const bf16* __restrict__ keff, bf16* __restrict__ kvT) {
  __shared__ bf16 tle[32][33];
  const int bx = blockIdx.x * 32;  // c
  const int by = blockIdx.y * 32;  // t
  const int x = threadIdx.x & 31, y = threadIdx.x >> 5; // 32x8
  for (int yy = y; yy < 32; yy += 8)
    tle[yy][x] = keff[(size_t)(by + yy) * 576 + bx + x];
  __syncthreads();
  for (int yy = y; yy < 32; yy += 8)
    kvT[(size_t)(bx + yy) * 2048 + by + x] = tle[x][yy];
}

// ---------------- row softmax, causal, in-place on S[h][q][0..2048) ---------
// One 256-thr block per (q, h). Row lives in regs (8 bf16/lane). Writes
// normalized P (bf16) for t<=q, zeros for t in (q, padend) where
// padend = round_up(q+1, 256) -- the K-clamped 256-row-tile PV GEMM never
// reads garbage.
__global__ void softmax_rows(bf16* __restrict__ S) {
  const int q = blockIdx.x, hh = blockIdx.y;
  bf16* row = S + ((size_t)hh * S_LEN + q) * S_LEN;
  const int tid = threadIdx.x, w = tid >> 6, lane = tid & 63;
  const int i0 = tid * 8;
  __shared__ float red[4];
  bf16x8 in = *(const bf16x8*)(row + i0);
  const float scale = 0.0721687836487032f;  // 1/sqrt(192)
  float v[8];
  float mx = -3e38f;
#pragma unroll
  for (int j = 0; j < 8; ++j) {
    v[j] = (i0 + j <= q) ? (float)in[j] * scale : -3e38f;
    mx = fmaxf(mx, v[j]);
  }
#pragma unroll
  for (int d = 1; d < 64; d <<= 1) mx = fmaxf(mx, __shfl_xor(mx, d, 64));
  if (lane == 0) red[w] = mx;
  __syncthreads();
  mx = fmaxf(fmaxf(red[0], red[1]), fmaxf(red[2], red[3]));
  __syncthreads();
  float p[8], sum = 0.f;
#pragma unroll
  for (int j = 0; j < 8; ++j) {
    p[j] = (i0 + j <= q) ? __expf(v[j] - mx) : 0.f;
    sum += p[j];
  }
#pragma unroll
  for (int d = 1; d < 64; d <<= 1) sum += __shfl_xor(sum, d, 64);
  if (lane == 0) red[w] = sum;
  __syncthreads();
  sum = red[0] + red[1] + red[2] + red[3];
  const float inv = 1.0f / sum;
  const int padend = ((q >> 8) + 1) << 8;   // 256-tile boundary
  if (i0 < padend) {
    bf16x8 o8;
#pragma unroll
    for (int j = 0; j < 8; ++j) o8[j] = (__bf16)__float2bfloat16(p[j] * inv);
    *(bf16x8*)(row + i0) = o8;
  }
}

// ---------------- GEMM: C[m][n] = sum_k A[m][k]*B[n][k] (+bias[n]) ----------
// BM x 128 tile (BM=128: 4 waves / BM=256: 8 waves), BK=64, mfma 16x16x32,
// global_load_lds staging, XCD-aware bijective block swizzle (nwg%8==0 at all
// call sites). mode 0: plain. mode 1: causal skip (n0 >= m0+BM), heavy rows
// first. mode 2: K clamped to m0+BM (PV over causal P), heavy rows first.
template <bool BIAS, bool BF16OUT, int BM>
__global__ __launch_bounds__(BM == 256 ? 512 : 256)
void gemm_bt(const bf16* __restrict__ A, const bf16* __restrict__ B,
             const float* __restrict__ bias, void* __restrict__ Cv,
             int lda, int ldb, int ldc, int K, int Nreal,
             long long bA, long long bB, long long bC, int mode) {
  // XCD swizzle: contiguous tile-chunk per XCD
  int bx, byi, bz;
  {
    const int gx = gridDim.x, gy = gridDim.y;
    const int nwg = gx * gy * (int)gridDim.z;
    const int lin = (int)blockIdx.x + gx * ((int)blockIdx.y + gy * (int)blockIdx.z);
    const int cpx = nwg >> 3;
    const int l2 = (lin & 7) * cpx + (lin >> 3);
    bx = l2 % gx;
    byi = (l2 / gx) % gy;
    bz = l2 / (gx * gy);
    if (mode) byi = gy - 1 - byi;  // heavy (large m0) first
  }
  const size_t m0 = (size_t)byi * BM, n0 = (size_t)bx * 128;
  if (mode == 1 && (int)n0 >= (int)m0 + BM) return;
  const int Keff = (mode == 2) ? ((K < (int)m0 + BM) ? K : (int)m0 + BM) : K;

  constexpr int NWAVES = (BM == 256) ? 8 : 4;
  constexpr int ACH = BM / 8;          // A chunks (1KB each)
  constexpr int TCH = ACH + 16;        // + B chunks
  constexpr int PER = TCH / NWAVES;    // chunks per wave (6 or 8)
  __shared__ bf16 As[BM * 64];
  __shared__ bf16 Bs[128 * 64];
  const int tid = threadIdx.x;
  const int wave = tid >> 6, lane = tid & 63;
  const int lo = lane & 15, hi = lane >> 4;
  const int wr = wave >> 1, wc = wave & 1;   // wr: 64-row stripe, wc: 64-col
  A += (size_t)bz * (size_t)bA;
  B += (size_t)bz * (size_t)bB;
  const int srow = lane >> 3;        // 0..7
  const int scol = (lane & 7) * 8;   // 0..56
  f32x4 acc[4][4] = {};
  for (int k0 = 0; k0 < Keff; k0 += 64) {
    __syncthreads();
#pragma unroll
    for (int i = 0; i < PER; ++i) {
      const int blk = wave * PER + i;
      if (blk < ACH) {
        const int row = blk * 8 + srow;
        gload16(A + (m0 + row) * (size_t)lda + k0 + scol, As + blk * 512);
      } else {
        const int j = blk - ACH;
        const int row = j * 8 + srow;
        gload16(B + (n0 + row) * (size_t)ldb + k0 + scol, Bs + j * 512);
      }
    }
    __syncthreads();
#pragma unroll
    for (int kk = 0; kk < 2; ++kk) {
      bf16x8 af[4], bfr[4];
#pragma unroll
      for (int m = 0; m < 4; ++m)
        af[m] = *(const bf16x8*)&As[(wr * 64 + m * 16 + lo) * 64 + kk * 32 + hi * 8];
#pragma unroll
      for (int n = 0; n < 4; ++n)
        bfr[n] = *(const bf16x8*)&Bs[(wc * 64 + n * 16 + lo) * 64 + kk * 32 + hi * 8];
#pragma unroll
      for (int m = 0; m < 4; ++m)
#pragma unroll
        for (int n = 0; n < 4; ++n)
          acc[m][n] = __builtin_amdgcn_mfma_f32_16x16x32_bf16(af[m], bfr[n], acc[m][n], 0, 0, 0);
    }
  }
  float* Cf = (float*)Cv;
  bf16* Cb = (bf16*)Cv;
  const size_t cbase = (size_t)bz * (size_t)bC;
#pragma unroll
  for (int m = 0; m < 4; ++m) {
    const size_t row = m0 + wr * 64 + m * 16 + hi * 4;
#pragma unroll
    for (int n = 0; n < 4; ++n) {
      const int col = (int)n0 + wc * 64 + n * 16 + lo;
      if (col < Nreal) {
        const float bv = BIAS ? bias[col] : 0.0f;
#pragma unroll
        for (int j = 0; j < 4; ++j) {
          const float v = acc[m][n][j] + bv;
          const size_t off = cbase + (row + j) * (size_t)ldc + col;
          if (BF16OUT) Cb[off] = __float2bfloat16(v);
          else         Cf[off] = v;
        }
      }
    }
  }
}

// ---------------------------------------------------------------------------
extern "C" void kernel_launch(void* const* d_in, const int* in_sizes, int n_in,
                              void* d_out, int out_size, void* d_ws, size_t ws_size,
                              hipStream_t stream) {
  const float* x       = (const float*)d_in[0];
  const float* wq_a_w  = (const float*)d_in[1];
  const float* wq_a_b  = (const float*)d_in[2];
  const float* q_norm  = (const float*)d_in[3];
  const float* wq_b_w  = (const float*)d_in[4];
  const float* wq_b_b  = (const float*)d_in[5];
  const float* wkv_a_w = (const float*)d_in[6];
  const float* wkv_a_b = (const float*)d_in[7];
  const float* kv_norm = (const float*)d_in[8];
  const float* wkv_b_w = (const float*)d_in[9];
  const float* wo_w    = (const float*)d_in[10];
  const float* wo_bias = (const float*)d_in[11];
  float* out = (float*)d_out;

  char* p = (char*)d_ws;
  auto alloc = [&](size_t bytes) {
    char* r = p;
    p += (bytes + 255) & ~(size_t)255;
    return r;
  };
  bf16*  xb    = (bf16*)alloc(2048ull * 2048 * 2);
  bf16*  wqa   = (bf16*)alloc(1536ull * 2048 * 2);
  bf16*  wqb   = (bf16*)alloc(3072ull * 1536 * 2);
  bf16*  wkva  = (bf16*)alloc(640ull * 2048 * 2);   // padded 576->640
  bf16*  wkvb  = (bf16*)alloc(4096ull * 512 * 2);
  bf16*  wob   = (bf16*)alloc(2048ull * 2048 * 2);
  bf16*  wkvbT = (bf16*)alloc(16ull * 512 * 128 * 2);
  bf16*  qa    = (bf16*)alloc(2048ull * 1536 * 2);
  bf16*  qn    = (bf16*)alloc(2048ull * 1536 * 2);
  bf16*  qv    = (bf16*)alloc(2048ull * 3072 * 2);
  float* kvf   = (float*)alloc(2048ull * 640 * 4);
  bf16*  keff  = (bf16*)alloc(2048ull * 576 * 2);
  bf16*  kvT   = (bf16*)alloc(512ull * 2048 * 2);
  bf16*  Qeff  = (bf16*)alloc(16ull * 2048 * 576 * 2);
  bf16*  attnb = (bf16*)alloc(16ull * 2048 * 512 * 2);
  bf16*  oabs  = (bf16*)alloc(2048ull * 2048 * 2);
  bf16*  Sbuf  = (bf16*)alloc(8ull * 2048 * 2048 * 2);  // 64MB, 8 heads/pass

  // weight / input converts (fp32 -> bf16, pad wkv_a rows to 640 with zeros)
  cvt_pad4<<<dim3(2048), 256, 0, stream>>>(x, xb, 2048, 2048, 2048);
  cvt_pad4<<<dim3(1024), 256, 0, stream>>>(wq_a_w, wqa, 1536, 2048, 1536);
  cvt_pad4<<<dim3(1024), 256, 0, stream>>>(wq_b_w, wqb, 3072, 1536, 3072);
  cvt_pad4<<<dim3(512), 256, 0, stream>>>(wkv_a_w, wkva, 576, 2048, 640);
  cvt_pad4<<<dim3(512), 256, 0, stream>>>(wkv_b_w, wkvb, 4096, 512, 4096);
  cvt_pad4<<<dim3(1024), 256, 0, stream>>>(wo_w, wob, 2048, 2048, 2048);
  mk_wkvbT<<<dim3(1024), 256, 0, stream>>>(wkvb, wkvbT);

  // q_a = rmsnorm(x @ wq_a^T + b)
  gemm_bt<true, true, 256><<<dim3(12, 8, 1), 512, 0, stream>>>(
      xb, wqa, wq_a_b, qa, 2048, 2048, 1536, 2048, 1536, 0, 0, 0, 0);
  rmsnorm_bf16<<<2048, 256, 0, stream>>>(qa, q_norm, qn, 1536);
  // q = qn @ wq_b^T + b  -> [2048][3072] (bf16)
  gemm_bt<true, true, 256><<<dim3(24, 8, 1), 512, 0, stream>>>(
      qn, wqb, wq_b_b, qv, 1536, 1536, 3072, 1536, 3072, 0, 0, 0, 0);
  // kv_full = x @ wkv_a^T + b -> fp32 [2048][640] (576 valid)
  gemm_bt<true, false, 256><<<dim3(5, 8, 1), 512, 0, stream>>>(
      xb, wkva, wkv_a_b, kvf, 2048, 2048, 640, 2048, 576, 0, 0, 0, 0);
  kv_post<<<2048, 256, 0, stream>>>(kvf, kv_norm, keff);
  transpose_k<<<dim3(16, 64), 256, 0, stream>>>(keff, kvT);
  q_post<<<2048, 256, 0, stream>>>(qv, Qeff);
  // absorbed q_nope: Qeff[h][s][0..512] = q_nope[s][h] @ wkv_bT[h]
  gemm_bt<false, true, 256><<<dim3(4, 8, 16), 512, 0, stream>>>(
      qv, wkvbT, nullptr, Qeff, 3072, 128, 576, 128, 512,
      192ll, 65536ll, 2048ll * 576, 0);

  // ---- attention via materialized S, 2 passes x 8 heads ----
  for (int pass = 0; pass < 2; ++pass) {
    const size_t h0 = (size_t)pass * 8;
    // S[h][q][t] = Qeff[h][q]·keff[t], causal block-skip
    gemm_bt<false, true, 256><<<dim3(16, 8, 8), 512, 0, stream>>>(
        Qeff + h0 * S_LEN * 576, keff, nullptr, Sbuf,
        576, 576, 2048, 576, 2048,
        2048ll * 576, 0, 2048ll * 2048, 1);
    // in-place row softmax with causal mask + 256-tile zero-pad
    softmax_rows<<<dim3(2048, 8), 256, 0, stream>>>(Sbuf);
    // attnb[h][q][c] = sum_t P[h][q][t] * kvT[c][t], K clamped to m0+256
    gemm_bt<false, true, 256><<<dim3(4, 8, 8), 512, 0, stream>>>(
        Sbuf, kvT, nullptr, attnb + h0 * S_LEN * 512,
        2048, 2048, 512, 2048, 512,
        2048ll * 2048, 0, 2048ll * 512, 2);
  }

  // output absorb: oabs[s][h*128+d] = attn[h][s] @ wkv_b[h][128+d][:]
  gemm_bt<false, true, 256><<<dim3(1, 8, 16), 512, 0, stream>>>(
      attnb, wkvb + 128ull * 512, nullptr, oabs, 512, 512, 2048, 512, 128,
      2048ll * 512, 256ll * 512, 128ll, 0);
  // final: out = oabs @ wo^T + b (fp32 out)
  gemm_bt<true, false, 256><<<dim3(16, 8, 1), 512, 0, stream>>>(
      oabs, wob, wo_bias, out, 2048, 2048, 2048, 2048, 2048, 0, 0, 0, 0);
}

// Round 8
// 477.983 us; speedup vs baseline: 1.3281x; 1.3281x over previous
//
#include <hip/hip_runtime.h>
#include <hip/hip_bf16.h>
#include <stdint.h>

// MLA forward, bf16 MFMA pipeline.
// Shapes: B=1 S=2048 HID=2048 H=16 QLR=1536 KVLR=512 NOPE=128 ROPE=64 VD=128 QKD=192.
// Attention = materialized-S: causal QK GEMM -> row softmax -> K-clamped PV GEMM.

using bf16 = __hip_bfloat16;
typedef __bf16 bf16x8 __attribute__((ext_vector_type(8)));
typedef __bf16 bf16x4 __attribute__((ext_vector_type(4)));
typedef float f32x4 __attribute__((ext_vector_type(4)));

#define S_LEN 2048
#define NHEAD 16

static __device__ __forceinline__ void gload16(const void* g, void* l) {
  __builtin_amdgcn_global_load_lds(
      (const __attribute__((address_space(1))) unsigned int*)g,
      (__attribute__((address_space(3))) unsigned int*)l, 16, 0, 0);
}

// ---------------- fp32 -> bf16 convert, 4-wide, optional row padding --------
__global__ void cvt_pad4(const float* __restrict__ src, bf16* __restrict__ dst,
                         int rows, int cols, int rowspad) {
  size_t total = ((size_t)rowspad * cols) >> 2;
  for (size_t i = (size_t)blockIdx.x * blockDim.x + threadIdx.x; i < total;
       i += (size_t)gridDim.x * blockDim.x) {
    size_t e = i << 2;
    int r = (int)(e / cols);
    int c = (int)(e % cols);
    float4 v;
    if (r < rows) v = *(const float4*)(src + (size_t)r * cols + c);
    else          v = make_float4(0.f, 0.f, 0.f, 0.f);
    bf16x4 o;
    o[0] = (__bf16)__float2bfloat16(v.x);
    o[1] = (__bf16)__float2bfloat16(v.y);
    o[2] = (__bf16)__float2bfloat16(v.z);
    o[3] = (__bf16)__float2bfloat16(v.w);
    *(bf16x4*)(dst + e) = o;
  }
}

// ---------------- wkv_bT[h][c][d] = wkv_b[h*256+d][c], d<128 ----------------
__global__ void mk_wkvbT(const bf16* __restrict__ wkvb, bf16* __restrict__ wt) {
  size_t total = 16ull * 512 * 128;
  for (size_t i = (size_t)blockIdx.x * blockDim.x + threadIdx.x; i < total;
       i += (size_t)gridDim.x * blockDim.x) {
    int h = (int)(i >> 16);          // 512*128
    int c = (int)((i >> 7) & 511);
    int d = (int)(i & 127);
    wt[i] = wkvb[((size_t)(h * 256 + d)) * 512 + c];
  }
}

// ---------------- row RMSNorm (bf16 in -> bf16 out) -------------------------
__global__ void rmsnorm_bf16(const bf16* __restrict__ in, const float* __restrict__ w,
                             bf16* __restrict__ out, int cols) {
  const int r = blockIdx.x, tid = threadIdx.x;
  const bf16* row = in + (size_t)r * cols;
  float ss = 0.f;
  for (int c = tid; c < cols; c += 256) {
    float v = __bfloat162float(row[c]);
    ss += v * v;
  }
  for (int m = 32; m >= 1; m >>= 1) ss += __shfl_xor(ss, m, 64);
  __shared__ float red[4];
  if ((tid & 63) == 0) red[tid >> 6] = ss;
  __syncthreads();
  ss = red[0] + red[1] + red[2] + red[3];
  float inv = rsqrtf(ss / (float)cols + 1e-6f);
  for (int c = tid; c < cols; c += 256)
    out[(size_t)r * cols + c] = __float2bfloat16(__bfloat162float(row[c]) * inv * w[c]);
}

// ---------------- kv post: rmsnorm(kv) + rope(k_pe) -> keff [t][576] --------
__global__ void kv_post(const float* __restrict__ kvf, const float* __restrict__ kvw,
                        bf16* __restrict__ keff) {
  const int t = blockIdx.x, tid = threadIdx.x;
  const float* row = kvf + (size_t)t * 640;
  float ss = 0.f;
  for (int c = tid; c < 512; c += 256) { float v = row[c]; ss += v * v; }
  for (int m = 32; m >= 1; m >>= 1) ss += __shfl_xor(ss, m, 64);
  __shared__ float red[4];
  if ((tid & 63) == 0) red[tid >> 6] = ss;
  __syncthreads();
  ss = red[0] + red[1] + red[2] + red[3];
  float inv = rsqrtf(ss * (1.0f / 512.0f) + 1e-6f);
  for (int c = tid; c < 512; c += 256)
    keff[(size_t)t * 576 + c] = __float2bfloat16(row[c] * inv * kvw[c]);
  if (tid < 64) {
    int j = tid, fr = j & 31;
    float freq = expf(-(float)fr * (1.0f / 32.0f) * 9.210340371976184f); // ln(10000)
    float ang = (float)t * freq;
    float cs = cosf(ang), sn = sinf(ang);
    float x1 = row[512 + j];
    float x2 = row[512 + (j < 32 ? j + 32 : j - 32)];
    float v = x1 * cs + (j < 32 ? -x2 : x2) * sn;
    keff[(size_t)t * 576 + 512 + j] = __float2bfloat16(v);
  }
}

// ---------------- q post: rope(q_pe) -> Qeff[h][s][512..576] ----------------
__global__ void q_post(const bf16* __restrict__ q, bf16* __restrict__ Qeff) {
  const int s = blockIdx.x, tid = threadIdx.x;
  for (int idx = tid; idx < 1024; idx += 256) {
    int h = idx >> 6, j = idx & 63, fr = j & 31;
    float freq = expf(-(float)fr * (1.0f / 32.0f) * 9.210340371976184f);
    float ang = (float)s * freq;
    float cs = cosf(ang), sn = sinf(ang);
    float x1 = __bfloat162float(q[(size_t)s * 3072 + h * 192 + 128 + j]);
    float x2 = __bfloat162float(q[(size_t)s * 3072 + h * 192 + 128 + (j < 32 ? j + 32 : j - 32)]);
    float v = x1 * cs + (j < 32 ? -x2 : x2) * sn;
    Qeff[((size_t)h * S_LEN + s) * 576 + 512 + j] = __float2bfloat16(v);
  }
}

// ---------------- kvT[c][t] = keff[t][c], c<512 (32x32 LDS transpose) -------
__global__ void transpose_k(const bf16* __restrict__ keff, bf16* __restrict__ kvT) {
  __shared__ bf16 tle[32][33];
  const int bx = blockIdx.x * 32;  // c
  const int by = blockIdx.y * 32;  // t
  const int x = threadIdx.x & 31, y = threadIdx.x >> 5; // 32x8
  for (int yy = y; yy < 32; yy += 8)
    tle[yy][x] = keff[(size_t)(by + yy) * 576 + bx + x];
  __syncthreads();
  for (int yy = y; yy < 32; yy += 8)
    kvT[(size_t)(bx + yy) * 2048 + by + x] = tle[x][yy];
}

// ---------------- row softmax, causal, in-place on S[h][q][0..2048) ---------
// One 256-thr block per (q, h). Row lives in regs (8 bf16/lane). Writes
// normalized P (bf16) for t<=q, zeros for t in (q, padend) where
// padend = round_up(q+1, 128) -- so the K-clamped PV GEMM never reads garbage.
__global__ void softmax_rows(bf16* __restrict__ S) {
  const int q = blockIdx.x, hh = blockIdx.y;
  bf16* row = S + ((size_t)hh * S_LEN + q) * S_LEN;
  const int tid = threadIdx.x, w = tid >> 6, lane = tid & 63;
  const int i0 = tid * 8;
  __shared__ float red[4];
  bf16x8 in = *(const bf16x8*)(row + i0);
  const float scale = 0.0721687836487032f;  // 1/sqrt(192)
  float v[8];
  float mx = -3e38f;
#pragma unroll
  for (int j = 0; j < 8; ++j) {
    v[j] = (i0 + j <= q) ? (float)in[j] * scale : -3e38f;
    mx = fmaxf(mx, v[j]);
  }
#pragma unroll
  for (int d = 1; d < 64; d <<= 1) mx = fmaxf(mx, __shfl_xor(mx, d, 64));
  if (lane == 0) red[w] = mx;
  __syncthreads();
  mx = fmaxf(fmaxf(red[0], red[1]), fmaxf(red[2], red[3]));
  __syncthreads();
  float p[8], sum = 0.f;
#pragma unroll
  for (int j = 0; j < 8; ++j) {
    p[j] = (i0 + j <= q) ? __expf(v[j] - mx) : 0.f;
    sum += p[j];
  }
#pragma unroll
  for (int d = 1; d < 64; d <<= 1) sum += __shfl_xor(sum, d, 64);
  if (lane == 0) red[w] = sum;
  __syncthreads();
  sum = red[0] + red[1] + red[2] + red[3];
  const float inv = 1.0f / sum;
  const int padend = ((q >> 7) + 1) << 7;
  if (i0 < padend) {
    bf16x8 o8;
#pragma unroll
    for (int j = 0; j < 8; ++j) o8[j] = (__bf16)__float2bfloat16(p[j] * inv);
    *(bf16x8*)(row + i0) = o8;
  }
}

// ---------------- GEMM: C[m][n] = sum_k A[m][k]*B[n][k] (+bias[n]) ----------
// 128x128 tile, BK=64, 4 waves, mfma 16x16x32, double-buffered LDS with
// prefetch-before-compute and ONE barrier per k-step (stage(t+1) latency
// hides under compute(t); barrier's implicit vmcnt drain lands after compute).
// XCD-aware bijective block swizzle (all call-site nwg % 8 == 0).
// mode 0: plain. mode 1: causal skip (n0 >= m0+128), heavy rows first.
// mode 2: K clamped to m0+128 (PV over causal P), heavy rows first.
template <bool BIAS, bool BF16OUT>
__global__ __launch_bounds__(256)
void gemm_bt(const bf16* __restrict__ A, const bf16* __restrict__ B,
             const float* __restrict__ bias, void* __restrict__ Cv,
             int lda, int ldb, int ldc, int K, int Nreal,
             long long bA, long long bB, long long bC, int mode) {
  // XCD swizzle: contiguous tile-chunk per XCD
  int bx, byi, bz;
  {
    const int gx = gridDim.x, gy = gridDim.y;
    const int nwg = gx * gy * (int)gridDim.z;
    const int lin = (int)blockIdx.x + gx * ((int)blockIdx.y + gy * (int)blockIdx.z);
    const int cpx = nwg >> 3;
    const int l2 = (lin & 7) * cpx + (lin >> 3);
    bx = l2 % gx;
    byi = (l2 / gx) % gy;
    bz = l2 / (gx * gy);
    if (mode) byi = gy - 1 - byi;  // heavy (large m0) first
  }
  const size_t m0 = (size_t)byi * 128, n0 = (size_t)bx * 128;
  if (mode == 1 && (int)n0 >= (int)m0 + 128) return;
  const int Keff = (mode == 2) ? ((K < (int)m0 + 128) ? K : (int)m0 + 128) : K;

  __shared__ bf16 As[2][8192];
  __shared__ bf16 Bs[2][8192];
  const int tid = threadIdx.x;
  const int wave = tid >> 6, lane = tid & 63;
  const int lo = lane & 15, hi = lane >> 4;
  const int wr = wave >> 1, wc = wave & 1;
  A += (size_t)bz * (size_t)bA;
  B += (size_t)bz * (size_t)bB;
  const int srow = lane >> 3;        // 0..7
  const int scol = (lane & 7) * 8;   // 0..56

  auto stage = [&](int k0, int buf) {
#pragma unroll
    for (int i = 0; i < 4; ++i) {
      const int blk = wave * 4 + i;        // 0..15 (1KB chunks)
      const int row = blk * 8 + srow;      // 0..127
      gload16(A + (m0 + row) * (size_t)lda + k0 + scol, &As[buf][blk * 512]);
      gload16(B + (n0 + row) * (size_t)ldb + k0 + scol, &Bs[buf][blk * 512]);
    }
  };

  f32x4 acc[4][4] = {};
  stage(0, 0);
  int cur = 0;
  for (int k0 = 0; k0 < Keff; k0 += 64) {
    __syncthreads();  // implicit vmcnt(0): buf[cur] ready; prev readers done
    if (k0 + 64 < Keff) stage(k0 + 64, cur ^ 1);
#pragma unroll
    for (int kk = 0; kk < 2; ++kk) {
      bf16x8 af[4], bfr[4];
#pragma unroll
      for (int m = 0; m < 4; ++m)
        af[m] = *(const bf16x8*)&As[cur][(wr * 64 + m * 16 + lo) * 64 + kk * 32 + hi * 8];
#pragma unroll
      for (int n = 0; n < 4; ++n)
        bfr[n] = *(const bf16x8*)&Bs[cur][(wc * 64 + n * 16 + lo) * 64 + kk * 32 + hi * 8];
#pragma unroll
      for (int m = 0; m < 4; ++m)
#pragma unroll
        for (int n = 0; n < 4; ++n)
          acc[m][n] = __builtin_amdgcn_mfma_f32_16x16x32_bf16(af[m], bfr[n], acc[m][n], 0, 0, 0);
    }
    cur ^= 1;
  }
  float* Cf = (float*)Cv;
  bf16* Cb = (bf16*)Cv;
  const size_t cbase = (size_t)bz * (size_t)bC;
#pragma unroll
  for (int m = 0; m < 4; ++m) {
    const size_t row = m0 + wr * 64 + m * 16 + hi * 4;
#pragma unroll
    for (int n = 0; n < 4; ++n) {
      const int col = (int)n0 + wc * 64 + n * 16 + lo;
      if (col < Nreal) {
        const float bv = BIAS ? bias[col] : 0.0f;
#pragma unroll
        for (int j = 0; j < 4; ++j) {
          const float v = acc[m][n][j] + bv;
          const size_t off = cbase + (row + j) * (size_t)ldc + col;
          if (BF16OUT) Cb[off] = __float2bfloat16(v);
          else         Cf[off] = v;
        }
      }
    }
  }
}

// ---------------------------------------------------------------------------
extern "C" void kernel_launch(void* const* d_in, const int* in_sizes, int n_in,
                              void* d_out, int out_size, void* d_ws, size_t ws_size,
                              hipStream_t stream) {
  const float* x       = (const float*)d_in[0];
  const float* wq_a_w  = (const float*)d_in[1];
  const float* wq_a_b  = (const float*)d_in[2];
  const float* q_norm  = (const float*)d_in[3];
  const float* wq_b_w  = (const float*)d_in[4];
  const float* wq_b_b  = (const float*)d_in[5];
  const float* wkv_a_w = (const float*)d_in[6];
  const float* wkv_a_b = (const float*)d_in[7];
  const float* kv_norm = (const float*)d_in[8];
  const float* wkv_b_w = (const float*)d_in[9];
  const float* wo_w    = (const float*)d_in[10];
  const float* wo_bias = (const float*)d_in[11];
  float* out = (float*)d_out;

  char* p = (char*)d_ws;
  auto alloc = [&](size_t bytes) {
    char* r = p;
    p += (bytes + 255) & ~(size_t)255;
    return r;
  };
  bf16*  xb    = (bf16*)alloc(2048ull * 2048 * 2);
  bf16*  wqa   = (bf16*)alloc(1536ull * 2048 * 2);
  bf16*  wqb   = (bf16*)alloc(3072ull * 1536 * 2);
  bf16*  wkva  = (bf16*)alloc(640ull * 2048 * 2);   // padded 576->640
  bf16*  wkvb  = (bf16*)alloc(4096ull * 512 * 2);
  bf16*  wob   = (bf16*)alloc(2048ull * 2048 * 2);
  bf16*  wkvbT = (bf16*)alloc(16ull * 512 * 128 * 2);
  bf16*  qa    = (bf16*)alloc(2048ull * 1536 * 2);
  bf16*  qn    = (bf16*)alloc(2048ull * 1536 * 2);
  bf16*  qv    = (bf16*)alloc(2048ull * 3072 * 2);
  float* kvf   = (float*)alloc(2048ull * 640 * 4);
  bf16*  keff  = (bf16*)alloc(2048ull * 576 * 2);
  bf16*  kvT   = (bf16*)alloc(512ull * 2048 * 2);
  bf16*  Qeff  = (bf16*)alloc(16ull * 2048 * 576 * 2);
  bf16*  attnb = (bf16*)alloc(16ull * 2048 * 512 * 2);
  bf16*  oabs  = (bf16*)alloc(2048ull * 2048 * 2);
  bf16*  Sbuf  = (bf16*)alloc(8ull * 2048 * 2048 * 2);  // 64MB, 8 heads/pass

  // weight / input converts (fp32 -> bf16, pad wkv_a rows to 640 with zeros)
  cvt_pad4<<<dim3(2048), 256, 0, stream>>>(x, xb, 2048, 2048, 2048);
  cvt_pad4<<<dim3(1024), 256, 0, stream>>>(wq_a_w, wqa, 1536, 2048, 1536);
  cvt_pad4<<<dim3(1024), 256, 0, stream>>>(wq_b_w, wqb, 3072, 1536, 3072);
  cvt_pad4<<<dim3(512), 256, 0, stream>>>(wkv_a_w, wkva, 576, 2048, 640);
  cvt_pad4<<<dim3(512), 256, 0, stream>>>(wkv_b_w, wkvb, 4096, 512, 4096);
  cvt_pad4<<<dim3(1024), 256, 0, stream>>>(wo_w, wob, 2048, 2048, 2048);
  mk_wkvbT<<<dim3(1024), 256, 0, stream>>>(wkvb, wkvbT);

  // q_a = rmsnorm(x @ wq_a^T + b)
  gemm_bt<true, true><<<dim3(12, 16, 1), 256, 0, stream>>>(
      xb, wqa, wq_a_b, qa, 2048, 2048, 1536, 2048, 1536, 0, 0, 0, 0);
  rmsnorm_bf16<<<2048, 256, 0, stream>>>(qa, q_norm, qn, 1536);
  // q = qn @ wq_b^T + b  -> [2048][3072] (bf16)
  gemm_bt<true, true><<<dim3(24, 16, 1), 256, 0, stream>>>(
      qn, wqb, wq_b_b, qv, 1536, 1536, 3072, 1536, 3072, 0, 0, 0, 0);
  // kv_full = x @ wkv_a^T + b -> fp32 [2048][640] (576 valid)
  gemm_bt<true, false><<<dim3(5, 16, 1), 256, 0, stream>>>(
      xb, wkva, wkv_a_b, kvf, 2048, 2048, 640, 2048, 576, 0, 0, 0, 0);
  kv_post<<<2048, 256, 0, stream>>>(kvf, kv_norm, keff);
  transpose_k<<<dim3(16, 64), 256, 0, stream>>>(keff, kvT);
  q_post<<<2048, 256, 0, stream>>>(qv, Qeff);
  // absorbed q_nope: Qeff[h][s][0..512] = q_nope[s][h] @ wkv_bT[h]
  gemm_bt<false, true><<<dim3(4, 16, 16), 256, 0, stream>>>(
      qv, wkvbT, nullptr, Qeff, 3072, 128, 576, 128, 512,
      192ll, 65536ll, 2048ll * 576, 0);

  // ---- attention via materialized S, 2 passes x 8 heads ----
  for (int pass = 0; pass < 2; ++pass) {
    const size_t h0 = (size_t)pass * 8;
    // S[h][q][t] = Qeff[h][q]·keff[t], causal block-skip
    gemm_bt<false, true><<<dim3(16, 16, 8), 256, 0, stream>>>(
        Qeff + h0 * S_LEN * 576, keff, nullptr, Sbuf,
        576, 576, 2048, 576, 2048,
        2048ll * 576, 0, 2048ll * 2048, 1);
    // in-place row softmax with causal mask + tile zero-pad
    softmax_rows<<<dim3(2048, 8), 256, 0, stream>>>(Sbuf);
    // attnb[h][q][c] = sum_t P[h][q][t] * kvT[c][t], K clamped to m0+128
    gemm_bt<false, true><<<dim3(4, 16, 8), 256, 0, stream>>>(
        Sbuf, kvT, nullptr, attnb + h0 * S_LEN * 512,
        2048, 2048, 512, 2048, 512,
        2048ll * 2048, 0, 2048ll * 512, 2);
  }

  // output absorb: oabs[s][h*128+d] = attn[h][s] @ wkv_b[h][128+d][:]
  gemm_bt<false, true><<<dim3(1, 16, 16), 256, 0, stream>>>(
      attnb, wkvb + 128ull * 512, nullptr, oabs, 512, 512, 2048, 512, 128,
      2048ll * 512, 256ll * 512, 128ll, 0);
  // final: out = oabs @ wo^T + b (fp32 out)
  gemm_bt<true, false><<<dim3(16, 16, 1), 256, 0, stream>>>(
      oabs, wob, wo_bias, out, 2048, 2048, 2048, 2048, 2048, 0, 0, 0, 0);
}